// Round 1
// baseline (838.249 us; speedup 1.0000x reference)
//
#include <hip/hip_runtime.h>
#include <hip/hip_bf16.h>
#include <math.h>

typedef __attribute__((ext_vector_type(8))) short bf16x8;
typedef __attribute__((ext_vector_type(4))) float f32x4;

#define MFMA16(a, b, c) __builtin_amdgcn_mfma_f32_16x16x32_bf16(a, b, c, 0, 0, 0)

__device__ inline unsigned short f2bf(float x) {
  union { float f; unsigned u; } v; v.f = x;
  unsigned r = v.u + 0x7FFFu + ((v.u >> 16) & 1u);
  return (unsigned short)(r >> 16);
}

// C[m,n] = sum_k A[m,k] * W[n,k]  (torch Linear, W row-major [N,K], K=128)
// A fp32 [M,128]; output bf16 [M,128] into out0 (blockIdx.y==0) or out1 (==1,
// using W rows 128..255). scale folded into output conversion.
__global__ __launch_bounds__(256) void proj_f32(
    const float* __restrict__ A, const float* __restrict__ W,
    unsigned short* __restrict__ out0, unsigned short* __restrict__ out1,
    float scale)
{
  const int mbase = blockIdx.x * 64;
  const int nt = blockIdx.y;
  unsigned short* outp = (nt == 0) ? out0 : out1;
  const float* Wp = W + (size_t)nt * 128 * 128;

  __shared__ unsigned short a_s[64 * 136];   // stride 136: 272B rows, 16B-aligned, 2-way-free banks
  __shared__ unsigned short w_s[128 * 136];

  const int tid = threadIdx.x;
  for (int p = 0; p < 8; ++p) {            // A tile 64x128 fp32 -> bf16
    int r = p * 8 + (tid >> 5);
    int c = tid & 31;
    float4 v = ((const float4*)(A + (size_t)(mbase + r) * 128))[c];
    unsigned short* d = &a_s[r * 136 + c * 4];
    d[0] = f2bf(v.x); d[1] = f2bf(v.y); d[2] = f2bf(v.z); d[3] = f2bf(v.w);
  }
  for (int p = 0; p < 16; ++p) {           // W tile 128x128 fp32 -> bf16
    int r = p * 8 + (tid >> 5);
    int c = tid & 31;
    float4 v = ((const float4*)(Wp + (size_t)r * 128))[c];
    unsigned short* d = &w_s[r * 136 + c * 4];
    d[0] = f2bf(v.x); d[1] = f2bf(v.y); d[2] = f2bf(v.z); d[3] = f2bf(v.w);
  }
  __syncthreads();

  const int wave = tid >> 6, lane = tid & 63, quad = lane >> 4, lr = lane & 15;
  f32x4 zero = {0.f, 0.f, 0.f, 0.f};
  f32x4 acc[8];
  for (int nb = 0; nb < 8; ++nb) acc[nb] = zero;

  for (int ks = 0; ks < 4; ++ks) {
    bf16x8 af = *(const bf16x8*)&a_s[(wave * 16 + lr) * 136 + ks * 32 + quad * 8];
    for (int nb = 0; nb < 8; ++nb) {
      bf16x8 bf = *(const bf16x8*)&w_s[(nb * 16 + lr) * 136 + ks * 32 + quad * 8];
      acc[nb] = MFMA16(af, bf, acc[nb]);
    }
  }
  for (int nb = 0; nb < 8; ++nb)
    for (int r = 0; r < 4; ++r) {
      int row = mbase + wave * 16 + quad * 4 + r;   // C/D: row = quad*4+reg
      int col = nb * 16 + lr;                       //      col = lane&15
      outp[(size_t)row * 128 + col] = f2bf(acc[nb][r] * scale);
    }
}

// Flash-style fused attention. qp pre-scaled by SCALE. Q-tile 128 (wave=32 rows),
// J-tile 64. kp_s holds K-tile [64][136] then is reused as P [128][72].
__global__ __launch_bounds__(256) void attn_fused(
    const unsigned short* __restrict__ qp,
    const unsigned short* __restrict__ kb,
    const unsigned short* __restrict__ vb,
    unsigned short* __restrict__ ao)
{
  const int bh = blockIdx.x >> 4;
  const int qt = blockIdx.x & 15;
  const size_t base = (size_t)bh * 2048 * 128;
  const unsigned short* Q = qp + base + (size_t)qt * 128 * 128;
  const unsigned short* K = kb + base;
  const unsigned short* V = vb + base;
  unsigned short* AO = ao + base + (size_t)qt * 128 * 128;

  __shared__ unsigned short kp_s[128 * 72];   // 18432 B (K view: [64][136] = 8704 elems fits)
  __shared__ unsigned short vT_s[128 * 72];   // [d][j], stride 72 (144B, 16B-aligned)

  const int tid = threadIdx.x;
  const int wave = tid >> 6, lane = tid & 63, quad = lane >> 4, lr = lane & 15;

  bf16x8 qf[2][4];  // Q fragments resident in regs for the whole kernel
  for (int mb = 0; mb < 2; ++mb)
    for (int ks = 0; ks < 4; ++ks)
      qf[mb][ks] = *(const bf16x8*)(Q + (size_t)(wave * 32 + mb * 16 + lr) * 128 + ks * 32 + quad * 8);

  f32x4 zero = {0.f, 0.f, 0.f, 0.f};
  f32x4 o_acc[2][8];
  float m_i[2][4], l_i[2][4];
  for (int mb = 0; mb < 2; ++mb) {
    for (int db = 0; db < 8; ++db) o_acc[mb][db] = zero;
    for (int r = 0; r < 4; ++r) { m_i[mb][r] = -1e30f; l_i[mb][r] = 0.f; }
  }

  for (int jt = 0; jt < 32; ++jt) {
    const unsigned short* Kt = K + (size_t)jt * 64 * 128;
    const unsigned short* Vt = V + (size_t)jt * 64 * 128;
    __syncthreads();  // previous iter's P/vT reads complete
    for (int p = 0; p < 4; ++p) {
      int r = p * 16 + (tid >> 4);
      int c = (tid & 15) * 8;
      *(bf16x8*)&kp_s[r * 136 + c] = *(const bf16x8*)(Kt + (size_t)r * 128 + c);
      bf16x8 tv = *(const bf16x8*)(Vt + (size_t)r * 128 + c);
      unsigned short* tvp = (unsigned short*)&tv;
      for (int u = 0; u < 8; ++u) vT_s[(c + u) * 72 + r] = tvp[u];  // transpose V
    }
    __syncthreads();

    // S = Q @ K^T  (scale pre-folded into qp)
    f32x4 s_acc[2][4];
    for (int mb = 0; mb < 2; ++mb) for (int nb = 0; nb < 4; ++nb) s_acc[mb][nb] = zero;
    for (int ks = 0; ks < 4; ++ks) {
      for (int nb = 0; nb < 4; ++nb) {
        bf16x8 kf = *(const bf16x8*)&kp_s[(nb * 16 + lr) * 136 + ks * 32 + quad * 8];
        s_acc[0][nb] = MFMA16(qf[0][ks], kf, s_acc[0][nb]);
        s_acc[1][nb] = MFMA16(qf[1][ks], kf, s_acc[1][nb]);
      }
    }
    __syncthreads();  // all waves done reading K before P overwrites kp_s

    // online softmax (rows live in C-layout: row = quad*4+r within the 16-block)
    for (int mb = 0; mb < 2; ++mb) {
      for (int r = 0; r < 4; ++r) {
        float mx = fmaxf(fmaxf(s_acc[mb][0][r], s_acc[mb][1][r]),
                         fmaxf(s_acc[mb][2][r], s_acc[mb][3][r]));
        for (int off = 1; off < 16; off <<= 1) mx = fmaxf(mx, __shfl_xor(mx, off));
        float mold = m_i[mb][r];
        float mnew = fmaxf(mold, mx);
        float alpha = __expf(mold - mnew);
        m_i[mb][r] = mnew;
        float rs = 0.f;
        for (int nb = 0; nb < 4; ++nb) {
          float pv = __expf(s_acc[mb][nb][r] - mnew);
          s_acc[mb][nb][r] = pv;
          rs += pv;
        }
        for (int off = 1; off < 16; off <<= 1) rs += __shfl_xor(rs, off);
        l_i[mb][r] = l_i[mb][r] * alpha + rs;
        for (int db = 0; db < 8; ++db) o_acc[mb][db][r] = o_acc[mb][db][r] * alpha;
        for (int nb = 0; nb < 4; ++nb)   // P -> LDS in A-operand layout (bf16)
          kp_s[(wave * 32 + mb * 16 + quad * 4 + r) * 72 + nb * 16 + lr] =
              f2bf(s_acc[mb][nb][r]);
      }
    }
    __syncthreads();

    // O += P @ V
    for (int ks = 0; ks < 2; ++ks) {
      bf16x8 pf0 = *(const bf16x8*)&kp_s[(wave * 32 + lr) * 72 + ks * 32 + quad * 8];
      bf16x8 pf1 = *(const bf16x8*)&kp_s[(wave * 32 + 16 + lr) * 72 + ks * 32 + quad * 8];
      for (int db = 0; db < 8; ++db) {
        bf16x8 vf = *(const bf16x8*)&vT_s[(db * 16 + lr) * 72 + ks * 32 + quad * 8];
        o_acc[0][db] = MFMA16(pf0, vf, o_acc[0][db]);
        o_acc[1][db] = MFMA16(pf1, vf, o_acc[1][db]);
      }
    }
  }

  for (int mb = 0; mb < 2; ++mb)
    for (int r = 0; r < 4; ++r) {
      float inv = 1.f / l_i[mb][r];
      int row = wave * 32 + mb * 16 + quad * 4 + r;
      for (int db = 0; db < 8; ++db) {
        int col = db * 16 + lr;
        AO[(size_t)row * 128 + col] = f2bf(o_acc[mb][db][r] * inv);
      }
    }
}

// out[m,e] = sum_d AO[m,d] * Wout[e,d] + bout[e], fp32 output
__global__ __launch_bounds__(256) void proj_out_k(
    const unsigned short* __restrict__ A, const float* __restrict__ W,
    const float* __restrict__ bias, float* __restrict__ out)
{
  const int mbase = blockIdx.x * 64;
  __shared__ unsigned short a_s[64 * 136];
  __shared__ unsigned short w_s[128 * 136];
  const int tid = threadIdx.x;
  for (int p = 0; p < 4; ++p) {
    int r = p * 16 + (tid >> 4);
    int c = (tid & 15) * 8;
    *(bf16x8*)&a_s[r * 136 + c] = *(const bf16x8*)(A + (size_t)(mbase + r) * 128 + c);
  }
  for (int p = 0; p < 16; ++p) {
    int r = p * 8 + (tid >> 5);
    int c = tid & 31;
    float4 v = ((const float4*)(W + (size_t)r * 128))[c];
    unsigned short* d = &w_s[r * 136 + c * 4];
    d[0] = f2bf(v.x); d[1] = f2bf(v.y); d[2] = f2bf(v.z); d[3] = f2bf(v.w);
  }
  __syncthreads();
  const int wave = tid >> 6, lane = tid & 63, quad = lane >> 4, lr = lane & 15;
  f32x4 zero = {0.f, 0.f, 0.f, 0.f};
  f32x4 acc[8];
  for (int nb = 0; nb < 8; ++nb) acc[nb] = zero;
  for (int ks = 0; ks < 4; ++ks) {
    bf16x8 af = *(const bf16x8*)&a_s[(wave * 16 + lr) * 136 + ks * 32 + quad * 8];
    for (int nb = 0; nb < 8; ++nb) {
      bf16x8 bf = *(const bf16x8*)&w_s[(nb * 16 + lr) * 136 + ks * 32 + quad * 8];
      acc[nb] = MFMA16(af, bf, acc[nb]);
    }
  }
  for (int nb = 0; nb < 8; ++nb)
    for (int r = 0; r < 4; ++r) {
      int row = mbase + wave * 16 + quad * 4 + r;
      int col = nb * 16 + lr;
      out[(size_t)row * 128 + col] = acc[nb][r] + bias[col];
    }
}

extern "C" void kernel_launch(void* const* d_in, const int* in_sizes, int n_in,
                              void* d_out, int out_size, void* d_ws, size_t ws_size,
                              hipStream_t stream) {
  const float* q    = (const float*)d_in[0];
  const float* kv   = (const float*)d_in[1];
  const float* Wq   = (const float*)d_in[2];
  const float* Wkv  = (const float*)d_in[3];
  const float* Wout = (const float*)d_in[4];
  const float* bout = (const float*)d_in[5];
  float* out = (float*)d_out;

  // ws carve: 4 bf16 buffers of 131072x128 = 32 MiB each (128 MiB total)
  const size_t NELEM = (size_t)131072 * 128;
  unsigned short* qp_b = (unsigned short*)d_ws;
  unsigned short* k_b  = qp_b + NELEM;
  unsigned short* v_b  = k_b + NELEM;
  unsigned short* ao_b = v_b + NELEM;

  const float SCALE = 0.08838834764831845f;  // 128^-0.5, folded into qp

  proj_f32<<<dim3(2048, 1), 256, 0, stream>>>(q, Wq, qp_b, qp_b, SCALE);
  proj_f32<<<dim3(2048, 2), 256, 0, stream>>>(kv, Wkv, k_b, v_b, 1.0f);
  attn_fused<<<dim3(1024), 256, 0, stream>>>(qp_b, k_b, v_b, ao_b);
  proj_out_k<<<dim3(2048), 256, 0, stream>>>(ao_b, Wout, bout, out);
}

// Round 2
// 647.493 us; speedup vs baseline: 1.2946x; 1.2946x over previous
//
#include <hip/hip_runtime.h>
#include <hip/hip_bf16.h>
#include <math.h>

typedef __attribute__((ext_vector_type(8))) short bf16x8;
typedef __attribute__((ext_vector_type(4))) unsigned short u16x4;
typedef __attribute__((ext_vector_type(4))) float f32x4;

#define MFMA16(a, b, c) __builtin_amdgcn_mfma_f32_16x16x32_bf16(a, b, c, 0, 0, 0)

__device__ inline unsigned short f2bf(float x) {
  union { float f; unsigned u; } v; v.f = x;
  unsigned r = v.u + 0x7FFFu + ((v.u >> 16) & 1u);
  return (unsigned short)(r >> 16);
}

// C[m,n] = sum_k A[m,k] * W[n,k]  (torch Linear, W row-major [N,K], K=128)
// A fp32 [M,128]; bf16 out. nt==0 -> out0 row-major [M,128] (scaled).
// nt==1 -> out1 is V^T: [bh][128][2048] (transposed store, rows m are j).
__global__ __launch_bounds__(256) void proj_f32(
    const float* __restrict__ A, const float* __restrict__ W,
    unsigned short* __restrict__ out0, unsigned short* __restrict__ out1,
    float scale)
{
  const int mbase = blockIdx.x * 64;
  const int nt = blockIdx.y;
  const float* Wp = W + (size_t)nt * 128 * 128;

  __shared__ unsigned short a_s[64 * 136];
  __shared__ unsigned short w_s[128 * 136];

  const int tid = threadIdx.x;
  for (int p = 0; p < 8; ++p) {            // A tile 64x128 fp32 -> bf16
    int r = p * 8 + (tid >> 5);
    int c = tid & 31;
    float4 v = ((const float4*)(A + (size_t)(mbase + r) * 128))[c];
    unsigned short* d = &a_s[r * 136 + c * 4];
    d[0] = f2bf(v.x); d[1] = f2bf(v.y); d[2] = f2bf(v.z); d[3] = f2bf(v.w);
  }
  for (int p = 0; p < 16; ++p) {           // W tile 128x128 fp32 -> bf16
    int r = p * 8 + (tid >> 5);
    int c = tid & 31;
    float4 v = ((const float4*)(Wp + (size_t)r * 128))[c];
    unsigned short* d = &w_s[r * 136 + c * 4];
    d[0] = f2bf(v.x); d[1] = f2bf(v.y); d[2] = f2bf(v.z); d[3] = f2bf(v.w);
  }
  __syncthreads();

  const int wave = tid >> 6, lane = tid & 63, quad = lane >> 4, lr = lane & 15;
  f32x4 zero = {0.f, 0.f, 0.f, 0.f};
  f32x4 acc[8];
  for (int nb = 0; nb < 8; ++nb) acc[nb] = zero;

  for (int ks = 0; ks < 4; ++ks) {
    bf16x8 af = *(const bf16x8*)&a_s[(wave * 16 + lr) * 136 + ks * 32 + quad * 8];
    for (int nb = 0; nb < 8; ++nb) {
      bf16x8 bf = *(const bf16x8*)&w_s[(nb * 16 + lr) * 136 + ks * 32 + quad * 8];
      acc[nb] = MFMA16(af, bf, acc[nb]);
    }
  }

  if (nt == 0) {
    for (int nb = 0; nb < 8; ++nb)
      for (int r = 0; r < 4; ++r) {
        int row = mbase + wave * 16 + quad * 4 + r;   // C/D: row = quad*4+reg
        int col = nb * 16 + lr;                       //      col = lane&15
        out0[(size_t)row * 128 + col] = f2bf(acc[nb][r] * scale);
      }
  } else {
    // transposed store: vT[bh][col][j], 4 consecutive j per lane -> 8B store
    int gm = mbase + wave * 16 + quad * 4;            // global row (j-index)
    int bh = gm >> 11;
    int j  = gm & 2047;
    unsigned short* vt = out1 + (size_t)bh * 128 * 2048;
    for (int nb = 0; nb < 8; ++nb) {
      int col = nb * 16 + lr;
      u16x4 pk;
      pk.x = f2bf(acc[nb][0]); pk.y = f2bf(acc[nb][1]);
      pk.z = f2bf(acc[nb][2]); pk.w = f2bf(acc[nb][3]);
      *(u16x4*)&vt[(size_t)col * 2048 + j] = pk;
    }
  }
}

// Flash-style fused attention. qp pre-scaled. Q-tile 128, J-tile 64.
// V comes in pre-transposed [bh][128][2048]. Separate K / vT / P LDS buffers:
// P is written+read by the same wave only -> no barrier around PV.
__global__ __launch_bounds__(256, 3) void attn_fused(
    const unsigned short* __restrict__ qp,
    const unsigned short* __restrict__ kb,
    const unsigned short* __restrict__ vTb,
    unsigned short* __restrict__ ao)
{
  const int bh = blockIdx.x >> 4;
  const int qt = blockIdx.x & 15;
  const unsigned short* Q  = qp  + (size_t)bh * 2048 * 128 + (size_t)qt * 128 * 128;
  const unsigned short* K  = kb  + (size_t)bh * 2048 * 128;
  const unsigned short* VT = vTb + (size_t)bh * 128 * 2048;
  unsigned short* AO = ao + (size_t)bh * 2048 * 128 + (size_t)qt * 128 * 128;

  __shared__ unsigned short k_s [64 * 136];   // K tile [j][d], stride 136
  __shared__ unsigned short vT_s[128 * 72];   // V^T tile [d][j], stride 72
  __shared__ unsigned short p_s [128 * 72];   // P tile [m][j], stride 72

  const int tid = threadIdx.x;
  const int wave = tid >> 6, lane = tid & 63, quad = lane >> 4, lr = lane & 15;

  bf16x8 qf[2][4];  // Q fragments resident for the whole kernel
  for (int mb = 0; mb < 2; ++mb)
    for (int ks = 0; ks < 4; ++ks)
      qf[mb][ks] = *(const bf16x8*)(Q + (size_t)(wave * 32 + mb * 16 + lr) * 128 + ks * 32 + quad * 8);

  f32x4 zero = {0.f, 0.f, 0.f, 0.f};
  f32x4 o_acc[2][8];
  float m_i[2][4], l_i[2][4];
  for (int mb = 0; mb < 2; ++mb) {
    for (int db = 0; db < 8; ++db) o_acc[mb][db] = zero;
    for (int r = 0; r < 4; ++r) { m_i[mb][r] = -1e30f; l_i[mb][r] = 0.f; }
  }

  for (int jt = 0; jt < 32; ++jt) {
    __syncthreads();  // all waves done reading k_s/vT_s from previous iter
    {
      const unsigned short* Kt = K + (size_t)jt * 64 * 128;
      int rk = (tid >> 4), ck = (tid & 15) * 8;
      for (int p = 0; p < 4; ++p)          // K: 64 rows x 256B, coalesced
        *(bf16x8*)&k_s[(p * 16 + rk) * 136 + ck] =
            *(const bf16x8*)(Kt + (size_t)(p * 16 + rk) * 128 + ck);
      int rv = (tid >> 3), cv = (tid & 7) * 8;
      for (int p = 0; p < 4; ++p)          // vT: 128 rows x 128B, coalesced
        *(bf16x8*)&vT_s[(p * 32 + rv) * 72 + cv] =
            *(const bf16x8*)(VT + (size_t)(p * 32 + rv) * 2048 + jt * 64 + cv);
    }
    __syncthreads();

    // S = Q @ K^T  (scale pre-folded into qp)
    f32x4 s_acc[2][4];
    for (int mb = 0; mb < 2; ++mb) for (int nb = 0; nb < 4; ++nb) s_acc[mb][nb] = zero;
    for (int ks = 0; ks < 4; ++ks) {
      for (int nb = 0; nb < 4; ++nb) {
        bf16x8 kf = *(const bf16x8*)&k_s[(nb * 16 + lr) * 136 + ks * 32 + quad * 8];
        s_acc[0][nb] = MFMA16(qf[0][ks], kf, s_acc[0][nb]);
        s_acc[1][nb] = MFMA16(qf[1][ks], kf, s_acc[1][nb]);
      }
    }

    // online softmax (C-layout rows: row = quad*4+r), P -> own rows of p_s
    for (int mb = 0; mb < 2; ++mb) {
      for (int r = 0; r < 4; ++r) {
        float mx = fmaxf(fmaxf(s_acc[mb][0][r], s_acc[mb][1][r]),
                         fmaxf(s_acc[mb][2][r], s_acc[mb][3][r]));
        for (int off = 1; off < 16; off <<= 1) mx = fmaxf(mx, __shfl_xor(mx, off));
        float mold = m_i[mb][r];
        float mnew = fmaxf(mold, mx);
        float alpha = __expf(mold - mnew);
        m_i[mb][r] = mnew;
        float rs = 0.f;
        for (int nb = 0; nb < 4; ++nb) {
          float pv = __expf(s_acc[mb][nb][r] - mnew);
          s_acc[mb][nb][r] = pv;
          rs += pv;
        }
        for (int off = 1; off < 16; off <<= 1) rs += __shfl_xor(rs, off);
        l_i[mb][r] = l_i[mb][r] * alpha + rs;
        for (int db = 0; db < 8; ++db) o_acc[mb][db][r] = o_acc[mb][db][r] * alpha;
        for (int nb = 0; nb < 4; ++nb)
          p_s[(wave * 32 + mb * 16 + quad * 4 + r) * 72 + nb * 16 + lr] =
              f2bf(s_acc[mb][nb][r]);
      }
    }
    // no barrier: each wave reads only its own P rows

    // O += P @ V
    for (int ks = 0; ks < 2; ++ks) {
      bf16x8 pf0 = *(const bf16x8*)&p_s[(wave * 32 + lr) * 72 + ks * 32 + quad * 8];
      bf16x8 pf1 = *(const bf16x8*)&p_s[(wave * 32 + 16 + lr) * 72 + ks * 32 + quad * 8];
      for (int db = 0; db < 8; ++db) {
        bf16x8 vf = *(const bf16x8*)&vT_s[(db * 16 + lr) * 72 + ks * 32 + quad * 8];
        o_acc[0][db] = MFMA16(pf0, vf, o_acc[0][db]);
        o_acc[1][db] = MFMA16(pf1, vf, o_acc[1][db]);
      }
    }
  }

  for (int mb = 0; mb < 2; ++mb)
    for (int r = 0; r < 4; ++r) {
      float inv = 1.f / l_i[mb][r];
      int row = wave * 32 + mb * 16 + quad * 4 + r;
      for (int db = 0; db < 8; ++db) {
        int col = db * 16 + lr;
        AO[(size_t)row * 128 + col] = f2bf(o_acc[mb][db][r] * inv);
      }
    }
}

// out[m,e] = sum_d AO[m,d] * Wout[e,d] + bout[e], fp32 output
__global__ __launch_bounds__(256) void proj_out_k(
    const unsigned short* __restrict__ A, const float* __restrict__ W,
    const float* __restrict__ bias, float* __restrict__ out)
{
  const int mbase = blockIdx.x * 64;
  __shared__ unsigned short a_s[64 * 136];
  __shared__ unsigned short w_s[128 * 136];
  const int tid = threadIdx.x;
  for (int p = 0; p < 4; ++p) {
    int r = p * 16 + (tid >> 4);
    int c = (tid & 15) * 8;
    *(bf16x8*)&a_s[r * 136 + c] = *(const bf16x8*)(A + (size_t)(mbase + r) * 128 + c);
  }
  for (int p = 0; p < 16; ++p) {
    int r = p * 8 + (tid >> 5);
    int c = tid & 31;
    float4 v = ((const float4*)(W + (size_t)r * 128))[c];
    unsigned short* d = &w_s[r * 136 + c * 4];
    d[0] = f2bf(v.x); d[1] = f2bf(v.y); d[2] = f2bf(v.z); d[3] = f2bf(v.w);
  }
  __syncthreads();
  const int wave = tid >> 6, lane = tid & 63, quad = lane >> 4, lr = lane & 15;
  f32x4 zero = {0.f, 0.f, 0.f, 0.f};
  f32x4 acc[8];
  for (int nb = 0; nb < 8; ++nb) acc[nb] = zero;
  for (int ks = 0; ks < 4; ++ks) {
    bf16x8 af = *(const bf16x8*)&a_s[(wave * 16 + lr) * 136 + ks * 32 + quad * 8];
    for (int nb = 0; nb < 8; ++nb) {
      bf16x8 bf = *(const bf16x8*)&w_s[(nb * 16 + lr) * 136 + ks * 32 + quad * 8];
      acc[nb] = MFMA16(af, bf, acc[nb]);
    }
  }
  for (int nb = 0; nb < 8; ++nb)
    for (int r = 0; r < 4; ++r) {
      int row = mbase + wave * 16 + quad * 4 + r;
      int col = nb * 16 + lr;
      out[(size_t)row * 128 + col] = acc[nb][r] + bias[col];
    }
}

extern "C" void kernel_launch(void* const* d_in, const int* in_sizes, int n_in,
                              void* d_out, int out_size, void* d_ws, size_t ws_size,
                              hipStream_t stream) {
  const float* q    = (const float*)d_in[0];
  const float* kv   = (const float*)d_in[1];
  const float* Wq   = (const float*)d_in[2];
  const float* Wkv  = (const float*)d_in[3];
  const float* Wout = (const float*)d_in[4];
  const float* bout = (const float*)d_in[5];
  float* out = (float*)d_out;

  // ws carve: 4 bf16 buffers of 131072x128 = 32 MiB each (128 MiB total)
  const size_t NELEM = (size_t)131072 * 128;
  unsigned short* qp_b = (unsigned short*)d_ws;
  unsigned short* k_b  = qp_b + NELEM;
  unsigned short* vT_b = k_b + NELEM;   // [bh][128][2048]
  unsigned short* ao_b = vT_b + NELEM;

  const float SCALE = 0.08838834764831845f;  // 128^-0.5, folded into qp

  proj_f32<<<dim3(2048, 1), 256, 0, stream>>>(q, Wq, qp_b, qp_b, SCALE);
  proj_f32<<<dim3(2048, 2), 256, 0, stream>>>(kv, Wkv, k_b, vT_b, 1.0f);
  attn_fused<<<dim3(1024), 256, 0, stream>>>(qp_b, k_b, vT_b, ao_b);
  proj_out_k<<<dim3(2048), 256, 0, stream>>>(ao_b, Wout, bout, out);
}